// Round 11
// baseline (113.353 us; speedup 1.0000x reference)
//
#include <hip/hip_runtime.h>

#define W 2048
#define H 2048
#define TX 64
#define TY 32
#define DW 92          // Ds row stride (floats); f4 row stride 23
#define DH 52          // TY + 20
#define HS 88          // Hs row stride; f4 row stride 22
// Ds col lc <-> img col gj = j0 - 12 + lc (lc 0..87); Ds row li <-> img row gi = i0 - 10 + li

typedef float f4 __attribute__((ext_vector_type(4)));

// DIAGNOSTIC BUILD rep=3: identical algorithm to R9, body executed three times per
// dispatch so the dispatch exceeds the ~43us harness fills and surfaces in rocprof
// top-5 with real counters (VGPR/occupancy/FETCH/VALUBusy). True kernel ~ dur - 23us.
__global__ __launch_bounds__(512, 8) void guided_fused(const float* __restrict__ X,
                                                       const float* __restrict__ y,
                                                       float* __restrict__ out) {
    __shared__ __align__(16) float Ds[DH * DW];   // 19.1 KB
    __shared__ __align__(16) float Hs[DH * HS];   // 18.3 KB

    const int tid = threadIdx.x;
    const int bx = blockIdx.x, by = blockIdx.y;
    const int i0 = by * TY, j0 = bx * TX;
    const bool interior = (bx >= 1) & (bx <= 30) & (by >= 1) & (by <= 62);
    const float R85 = 0.011764706f;               // 1/85

    for (int rep = 0; rep < 3; ++rep) {

    // ---- S1: D = y - X over 52 rows x 22 aligned f4 col-groups ----
    if (interior) {
        #pragma unroll
        for (int k = 0; k < 3; ++k) {
            int c = tid + k * 512;
            if (c < DH * 22) {
                int li = c / 22, g = c - li * 22;
                int off = (i0 - 10 + li) * W + (j0 - 12) + 4 * g;   // 16B aligned
                f4 yv = *(const f4*)&y[off];
                f4 xv = *(const f4*)&X[off];
                *(f4*)&Ds[li * DW + 4 * g] = yv - xv;
            }
        }
    } else {
        #pragma unroll
        for (int k = 0; k < 3; ++k) {
            int c = tid + k * 512;
            if (c < DH * 22) {
                int li = c / 22, g = c - li * 22;
                int gi = i0 - 10 + li, gj = j0 - 12 + 4 * g;
                f4 d = {0.f, 0.f, 0.f, 0.f};
                if ((unsigned)gi < H) {
                    if (gj >= 0 && gj + 3 < W) {
                        f4 yv = *(const f4*)&y[gi * W + gj];
                        f4 xv = *(const f4*)&X[gi * W + gj];
                        d = yv - xv;
                    } else {
                        #pragma unroll
                        for (int e = 0; e < 4; ++e) {
                            int gc = gj + e;
                            if ((unsigned)gc < W) d[e] = y[gi * W + gc] - X[gi * W + gc];
                        }
                    }
                }
                *(f4*)&Ds[li * DW + 4 * g] = d;
            }
        }
    }
    __syncthreads();

    // ---- S2: H[r][4g..4g+3] = hsum5(D row r); 1040 tasks ----
    #pragma unroll
    for (int k = 0; k < 3; ++k) {
        int c = tid + k * 512;
        if (c < DH * 20) {
            int r = c / 20, g = c - r * 20;
            const f4* dp = (const f4*)&Ds[r * DW + 4 * g];
            f4 a = dp[0], b = dp[1], cc = dp[2];
            float sb123 = b.y + b.z;
            float h = b.x + sb123;
            f4 o;
            o.x = a.z + a.w + h;
            o.y = a.w + h + b.w;
            o.z = h + b.w + cc.x;
            o.w = sb123 + b.w + cc.x + cc.y;
            *(f4*)&Hs[r * HS + 4 * g] = o;
        }
    }
    __syncthreads();

    // ---- S3: D2 = D - vsum17(H)/Ni1, in-place f4 RMW; 180 tasks ----
    if (tid < 180) {
        int seg = tid / 20, g = tid - seg * 20;
        int v0 = seg * 4;
        const f4* hp = (const f4*)&Hs[v0 * HS + 4 * g];
        f4 r0 = hp[0], r1 = hp[22], r2 = hp[44];
        f4 s = r0 + r1 + r2;
        #pragma unroll
        for (int t = 3; t < 17; ++t) s += hp[t * 22];
        #pragma unroll
        for (int k = 0; k < 4; ++k) {
            int v = v0 + k;
            int off = (v + 8) * DW + 4 * g + 4;
            f4 d2 = *(const f4*)&Ds[off];
            if (interior) {
                d2 -= s * R85;
            } else {
                int gi = i0 + v - 2;
                if ((unsigned)gi < H) {
                    int r0c = gi - 8 > 0 ? gi - 8 : 0;
                    int r1c = gi + 8 < H - 1 ? gi + 8 : H - 1;
                    float rowsN = (float)(r1c - r0c + 1);
                    #pragma unroll
                    for (int e = 0; e < 4; ++e) {
                        int gj = j0 - 8 + 4 * g + e;
                        if ((unsigned)gj < W) {
                            int c0 = gj - 2 > 0 ? gj - 2 : 0;
                            int c1 = gj + 2 < W - 1 ? gj + 2 : W - 1;
                            d2[e] -= s[e] * __builtin_amdgcn_rcpf(rowsN * (float)(c1 - c0 + 1));
                        }
                    }
                }
            }
            *(f4*)&Ds[off] = d2;
            if (k < 3) s += hp[(k + 17) * 22] - hp[k * 22];
        }
    }
    __syncthreads();

    // ---- S4: V2[w] = vsum5(D2 rows w..w+4); 320 tasks ----
    if (tid < 320) {
        int seg = tid / 20, g = tid - seg * 20;
        int w0 = seg * 2;
        const f4* dp = (const f4*)&Ds[(w0 + 8) * DW + 4 * g + 4];
        f4 r0 = dp[0];
        f4 s = r0 + dp[23] + dp[46] + dp[69] + dp[92];
        f4* vp = (f4*)&Hs[w0 * HS + 4 * g];
        vp[0] = s;
        s += dp[115] - r0; vp[22] = s;
    }
    __syncthreads();

    // ---- S5: out = y - D2 + hsum17(V2)/Ni2; 512 tasks ----
    {
        int w = tid >> 4, x0 = (tid & 15) * 4;
        int gbase = (i0 + w) * W + j0 + x0;
        f4 yv = *(const f4*)&y[gbase];
        float val[20];
        const f4* vp = (const f4*)&Hs[w * HS + x0];
        #pragma unroll
        for (int q = 0; q < 5; ++q) {
            f4 tq = vp[q];
            val[q * 4 + 0] = tq.x; val[q * 4 + 1] = tq.y;
            val[q * 4 + 2] = tq.z; val[q * 4 + 3] = tq.w;
        }
        float s = 0.f;
        #pragma unroll
        for (int c = 0; c < 17; ++c) s += val[c];
        f4 d2 = *(const f4*)&Ds[(w + 10) * DW + x0 + 12];
        f4 o;
        if (interior) {
            o.x = yv.x - d2.x + s * R85;
            s += val[17] - val[0];
            o.y = yv.y - d2.y + s * R85;
            s += val[18] - val[1];
            o.z = yv.z - d2.z + s * R85;
            s += val[19] - val[2];
            o.w = yv.w - d2.w + s * R85;
        } else {
            int gi = i0 + w;
            int r0c = gi - 2 > 0 ? gi - 2 : 0;
            int r1c = gi + 2 < H - 1 ? gi + 2 : H - 1;
            float rowsN = (float)(r1c - r0c + 1);
            float res[4];
            #pragma unroll
            for (int e = 0; e < 4; ++e) {
                int gj = j0 + x0 + e;
                int c0 = gj - 8 > 0 ? gj - 8 : 0;
                int c1 = gj + 8 < W - 1 ? gj + 8 : W - 1;
                res[e] = s * __builtin_amdgcn_rcpf(rowsN * (float)(c1 - c0 + 1));
                if (e < 3) s += val[e + 17] - val[e];
            }
            o.x = yv.x - d2.x + res[0];
            o.y = yv.y - d2.y + res[1];
            o.z = yv.z - d2.z + res[2];
            o.w = yv.w - d2.w + res[3];
        }
        *(f4*)&out[gbase] = o;
    }
    __syncthreads();   // protect Ds/Hs before next rep's S1 overwrite

    } // rep
}

extern "C" void kernel_launch(void* const* d_in, const int* in_sizes, int n_in,
                              void* d_out, int out_size, void* d_ws, size_t ws_size,
                              hipStream_t stream) {
    const float* X = (const float*)d_in[0];
    const float* y = (const float*)d_in[1];
    float* out = (float*)d_out;

    dim3 blk(512, 1, 1);
    dim3 grd(W / TX, H / TY, 1);   // 32 x 64 = 2048 blocks
    guided_fused<<<grd, blk, 0, stream>>>(X, y, out);
}

// Round 12
// 95.003 us; speedup vs baseline: 1.1932x; 1.1932x over previous
//
#include <hip/hip_runtime.h>

#define W 2048
#define H 2048
#define TX 64
#define TY 32
#define DW 92          // Ds row stride (floats); f4 row stride 23
#define DH 52          // TY + 20
#define HS 88          // Hs row stride; f4 row stride 22
// Ds col lc <-> img col gj = j0 - 12 + lc (lc 0..87); Ds row li <-> img row gi = i0 - 10 + li

typedef float f4 __attribute__((ext_vector_type(4)));

// Fused guided-filter update, TWO vertically-adjacent tiles per block with
// REGISTER prefetch: tile B's global loads issue before tile A's compute, so
// B's HBM latency hides under A's LDS/VALU phases. LDS is reused (not doubled),
// keeping 4 blocks/CU. Algorithm identical to R9 (hsum-first pass 1).
__global__ __launch_bounds__(512, 8) void guided_fused(const float* __restrict__ X,
                                                       const float* __restrict__ y,
                                                       float* __restrict__ out) {
    __shared__ __align__(16) float Ds[DH * DW];   // 19.1 KB: D, then D2 in-place
    __shared__ __align__(16) float Hs[DH * HS];   // 18.3 KB: H (pass1), then V2 (pass2)

    const int tid = threadIdx.x;
    const int bx = blockIdx.x, byp = blockIdx.y;
    const int j0 = bx * TX;
    const int i0A = (2 * byp) * TY;
    const int i0B = i0A + TY;
    const bool xin = (bx >= 1) & (bx <= 30);
    const bool intA = xin & (byp >= 1);
    const bool intB = xin & (byp <= 30);
    const float R85 = 0.011764706f;               // 1/85

    f4 ry[3], rx[3];                              // prefetch regs (24 VGPR)

    // Issue global loads for one tile into ry/rx (no arithmetic on them here,
    // so no waitcnt is needed until the store phase).
    auto load_tile_regs = [&](int i0, bool interior) {
        #pragma unroll
        for (int k = 0; k < 3; ++k) {
            int c = tid + k * 512;
            ry[k] = (f4){0.f, 0.f, 0.f, 0.f};
            rx[k] = (f4){0.f, 0.f, 0.f, 0.f};
            if (c < DH * 22) {
                int li = c / 22, g = c - li * 22;
                int gi = i0 - 10 + li, gj = j0 - 12 + 4 * g;
                if (interior) {
                    int off = gi * W + gj;                    // 16B aligned
                    ry[k] = *(const f4*)&y[off];
                    rx[k] = *(const f4*)&X[off];
                } else if ((unsigned)gi < H) {
                    if (gj >= 0 && gj + 3 < W) {
                        ry[k] = *(const f4*)&y[gi * W + gj];
                        rx[k] = *(const f4*)&X[gi * W + gj];
                    } else {
                        #pragma unroll
                        for (int e = 0; e < 4; ++e) {
                            int gc = gj + e;
                            if ((unsigned)gc < W) {
                                ry[k][e] = y[gi * W + gc];
                                rx[k][e] = X[gi * W + gc];
                            }
                        }
                    }
                }
            }
        }
    };

    // D = y - X into LDS (first use of ry/rx -> vmcnt wait lands here).
    auto store_tile_lds = [&]() {
        #pragma unroll
        for (int k = 0; k < 3; ++k) {
            int c = tid + k * 512;
            if (c < DH * 22) {
                int li = c / 22, g = c - li * 22;
                *(f4*)&Ds[li * DW + 4 * g] = ry[k] - rx[k];
            }
        }
    };

    auto compute_tile = [&](int i0, bool interior) {
        // ---- S2: H[r][4g..4g+3] = hsum5(D row r); 1040 tasks ----
        #pragma unroll
        for (int k = 0; k < 3; ++k) {
            int c = tid + k * 512;
            if (c < DH * 20) {
                int r = c / 20, g = c - r * 20;
                const f4* dp = (const f4*)&Ds[r * DW + 4 * g];
                f4 a = dp[0], b = dp[1], cc = dp[2];
                float sb123 = b.y + b.z;
                float h = b.x + sb123;
                f4 o;
                o.x = a.z + a.w + h;
                o.y = a.w + h + b.w;
                o.z = h + b.w + cc.x;
                o.w = sb123 + b.w + cc.x + cc.y;
                *(f4*)&Hs[r * HS + 4 * g] = o;
            }
        }
        __syncthreads();

        // ---- S3: D2 = D - vsum17(H)/Ni1, in-place f4 RMW; 180 tasks ----
        if (tid < 180) {
            int seg = tid / 20, g = tid - seg * 20;
            int v0 = seg * 4;
            const f4* hp = (const f4*)&Hs[v0 * HS + 4 * g];
            f4 r0 = hp[0], r1 = hp[22], r2 = hp[44];
            f4 s = r0 + r1 + r2;
            #pragma unroll
            for (int t = 3; t < 17; ++t) s += hp[t * 22];
            #pragma unroll
            for (int k = 0; k < 4; ++k) {
                int v = v0 + k;
                int off = (v + 8) * DW + 4 * g + 4;
                f4 d2 = *(const f4*)&Ds[off];
                if (interior) {
                    d2 -= s * R85;
                } else {
                    int gi = i0 + v - 2;
                    if ((unsigned)gi < H) {
                        int r0c = gi - 8 > 0 ? gi - 8 : 0;
                        int r1c = gi + 8 < H - 1 ? gi + 8 : H - 1;
                        float rowsN = (float)(r1c - r0c + 1);
                        #pragma unroll
                        for (int e = 0; e < 4; ++e) {
                            int gj = j0 - 8 + 4 * g + e;
                            if ((unsigned)gj < W) {
                                int c0 = gj - 2 > 0 ? gj - 2 : 0;
                                int c1 = gj + 2 < W - 1 ? gj + 2 : W - 1;
                                d2[e] -= s[e] * __builtin_amdgcn_rcpf(rowsN * (float)(c1 - c0 + 1));
                            }
                        }
                    }
                }
                *(f4*)&Ds[off] = d2;
                if (k < 3) s += hp[(k + 17) * 22] - hp[k * 22];
            }
        }
        __syncthreads();

        // ---- S4: V2[w] = vsum5(D2 rows w..w+4); 320 tasks ----
        if (tid < 320) {
            int seg = tid / 20, g = tid - seg * 20;
            int w0 = seg * 2;
            const f4* dp = (const f4*)&Ds[(w0 + 8) * DW + 4 * g + 4];
            f4 r0 = dp[0];
            f4 s = r0 + dp[23] + dp[46] + dp[69] + dp[92];
            f4* vp = (f4*)&Hs[w0 * HS + 4 * g];
            vp[0] = s;
            s += dp[115] - r0; vp[22] = s;
        }
        __syncthreads();

        // ---- S5: out = y - D2 + hsum17(V2)/Ni2; 512 tasks (low-register form) ----
        {
            int w = tid >> 4, x0 = (tid & 15) * 4;
            int gbase = (i0 + w) * W + j0 + x0;
            f4 yv = *(const f4*)&y[gbase];               // L2-hot re-read
            const f4* vp = (const f4*)&Hs[w * HS + x0];
            f4 v0 = vp[0], v4 = vp[4];
            f4 t = v0 + vp[1] + vp[2] + vp[3];
            float s = t.x + t.y + t.z + t.w + v4.x;      // sum of 17 taps
            f4 d2 = *(const f4*)&Ds[(w + 10) * DW + x0 + 12];
            f4 o;
            if (interior) {
                o.x = yv.x - d2.x + s * R85;
                s += v4.y - v0.x;
                o.y = yv.y - d2.y + s * R85;
                s += v4.z - v0.y;
                o.z = yv.z - d2.z + s * R85;
                s += v4.w - v0.z;
                o.w = yv.w - d2.w + s * R85;
            } else {
                int gi = i0 + w;
                int r0c = gi - 2 > 0 ? gi - 2 : 0;
                int r1c = gi + 2 < H - 1 ? gi + 2 : H - 1;
                float rowsN = (float)(r1c - r0c + 1);
                float sl0 = v4.y - v0.x, sl1 = v4.z - v0.y, sl2 = v4.w - v0.z;
                float res[4];
                #pragma unroll
                for (int e = 0; e < 4; ++e) {
                    int gj = j0 + x0 + e;
                    int c0 = gj - 8 > 0 ? gj - 8 : 0;
                    int c1 = gj + 8 < W - 1 ? gj + 8 : W - 1;
                    res[e] = s * __builtin_amdgcn_rcpf(rowsN * (float)(c1 - c0 + 1));
                    if (e == 0) s += sl0;
                    if (e == 1) s += sl1;
                    if (e == 2) s += sl2;
                }
                o.x = yv.x - d2.x + res[0];
                o.y = yv.y - d2.y + res[1];
                o.z = yv.z - d2.z + res[2];
                o.w = yv.w - d2.w + res[3];
            }
            *(f4*)&out[gbase] = o;
        }
    };

    // ---------------- schedule: A-load, A-store, [B-load issue], A-compute,
    //                  barrier, B-store (vmcnt lands here), B-compute ---------
    load_tile_regs(i0A, intA);
    store_tile_lds();
    __syncthreads();

    load_tile_regs(i0B, intB);      // in flight during compute_tile(A)
    compute_tile(i0A, intA);
    __syncthreads();                // Ds/Hs free for reuse

    store_tile_lds();
    __syncthreads();
    compute_tile(i0B, intB);
}

extern "C" void kernel_launch(void* const* d_in, const int* in_sizes, int n_in,
                              void* d_out, int out_size, void* d_ws, size_t ws_size,
                              hipStream_t stream) {
    const float* X = (const float*)d_in[0];
    const float* y = (const float*)d_in[1];
    float* out = (float*)d_out;

    dim3 blk(512, 1, 1);
    dim3 grd(W / TX, H / (2 * TY), 1);   // 32 x 32 = 1024 tile-pair blocks
    guided_fused<<<grd, blk, 0, stream>>>(X, y, out);
}